// Round 10
// baseline (223.076 us; speedup 1.0000x reference)
//
#include <hip/hip_runtime.h>

#define DIM 128
#define BINSHIFT 7
#define BINSZ 128          // nodes per bin
#define BCAP 2560          // edges capacity per bin: Poisson(2048)+11sigma
#define EPB 8192           // edges per binning block

typedef __attribute__((ext_vector_type(8))) short bf16x8;
typedef __attribute__((ext_vector_type(4))) float f32x4;

__device__ inline unsigned short f2b(float f) {
    unsigned u = __builtin_bit_cast(unsigned, f);
    unsigned r = (u + 0x7FFFu + ((u >> 16) & 1u)) >> 16;
    return (unsigned short)r;
}
__device__ inline float b2f(unsigned short h) {
    unsigned u = ((unsigned)h) << 16;
    return __builtin_bit_cast(float, u);
}

// ---------------------------------------------------------------- prep: [0,ebB) bin edges | [ebB,ebB+castB) cast x | last 8: W1/W2 -> bf16 W^T
__global__ __launch_bounds__(1024)
void prep(const int* __restrict__ src, const int* __restrict__ dst,
          unsigned* __restrict__ gcur, unsigned* __restrict__ binned, int E, int nbins,
          const float* __restrict__ x, unsigned short* __restrict__ xb, int n8,
          const float* __restrict__ W1, const float* __restrict__ W2,
          unsigned short* __restrict__ wT1, unsigned short* __restrict__ wT2,
          int ebB, int castB)
{
    const int t = threadIdx.x;
    const int bid = blockIdx.x;
    if (bid < ebB) {
        // ---- binning role (proven) ----
        __shared__ unsigned hist[1024];
        __shared__ unsigned base[1024];
        const long long bb = (long long)bid * EPB;
        if (t < nbins) hist[t] = 0;
        __syncthreads();
        unsigned pk[8], pos[8];
        int bn[8];
        bool ok[8];
        #pragma unroll
        for (int i = 0; i < 8; ++i) {
            long long idx = bb + i * 1024 + t;
            ok[i] = idx < E;
            if (ok[i]) {
                int s = src[idx], d = dst[idx];
                pk[i] = ((unsigned)(d & (BINSZ - 1)) << 17) | (unsigned)s;
                bn[i] = d >> BINSHIFT;
                pos[i] = atomicAdd(&hist[bn[i]], 1u);
            }
        }
        __syncthreads();
        if (t < nbins) base[t] = (unsigned)t * BCAP + atomicAdd(&gcur[t], hist[t]);
        __syncthreads();
        #pragma unroll
        for (int i = 0; i < 8; ++i) {
            if (ok[i]) {
                unsigned off = base[bn[i]] + pos[i];
                if (off < (unsigned)(bn[i] + 1) * BCAP) binned[off] = pk[i];
            }
        }
    } else if (bid < ebB + castB) {
        // ---- cast x role ----
        int i = (bid - ebB) * 1024 + t;
        if (i >= n8) return;
        float4 a = ((const float4*)x)[i * 2];
        float4 b = ((const float4*)x)[i * 2 + 1];
        bf16x8 o;
        o[0] = (short)f2b(a.x); o[1] = (short)f2b(a.y); o[2] = (short)f2b(a.z); o[3] = (short)f2b(a.w);
        o[4] = (short)f2b(b.x); o[5] = (short)f2b(b.y); o[6] = (short)f2b(b.z); o[7] = (short)f2b(b.w);
        ((bf16x8*)xb)[i] = o;
    } else {
        // ---- W transpose+cast role: 4 blocks per weight ----
        int r = bid - ebB - castB;                 // 0..7
        const float* Ws = (r < 4) ? W1 : W2;
        unsigned short* wt = (r < 4) ? wT1 : wT2;
        int idx = (r & 3) * 1024 + t;              // 0..4095
        int n = idx >> 5, k = (idx & 31) * 4;
        #pragma unroll
        for (int i = 0; i < 4; ++i)
            wt[n * 128 + k + i] = f2b(Ws[(size_t)(k + i) * 128 + n]);
    }
}

// ---------------------------------------------------------------- fused: LDS counting-sort + register-fragment gather + MFMA GEMM1
// 512 threads, one bin of 128 nodes. Thread (wave,rl,kg): node=wave*16+rl,
// gathers channels kk*32+kg*8 (kk=0..3) = its MFMA A-fragments directly.
__global__ __launch_bounds__(512)
void agg_gemm1(const unsigned short* __restrict__ xb, const float* __restrict__ epsp,
               const unsigned* __restrict__ gcur, const unsigned* __restrict__ binned,
               const unsigned short* __restrict__ wT, const float* __restrict__ bias,
               unsigned short* __restrict__ h1b, float* __restrict__ stats, int N)
{
    __shared__ unsigned ssrt[BCAP];            // 10 KB
    __shared__ unsigned hist[BINSZ], sbase[BINSZ], cur[BINSZ];
    __shared__ unsigned wtot_s;
    __shared__ float red[256];
    const int t = threadIdx.x;
    const int bin = blockIdx.x;
    const int node0 = bin << BINSHIFT;

    if (t < BINSZ) hist[t] = 0;
    if (t < 256) red[t] = 0.f;
    __syncthreads();

    int cnt = (int)gcur[bin];
    if (cnt > BCAP) cnt = BCAP;
    const unsigned* __restrict__ bp = binned + (size_t)bin * BCAP;
    for (int i = t; i < cnt; i += 512)
        atomicAdd(&hist[(bp[i] >> 17) & (BINSZ - 1)], 1u);
    __syncthreads();

    // parallel exclusive scan of hist[128] (two waves, shfl_up)
    unsigned iv = 0, hv = 0;
    if (t < BINSZ) {
        hv = hist[t];
        iv = hv;
        #pragma unroll
        for (int d = 1; d < 64; d <<= 1) {
            unsigned u = __shfl_up(iv, d);
            if ((t & 63) >= d) iv += u;
        }
        if (t == 63) wtot_s = iv;
    }
    __syncthreads();
    if (t < BINSZ) {
        unsigned ex = iv - hv + ((t >= 64) ? wtot_s : 0u);
        sbase[t] = ex;
        cur[t] = ex;
    }
    __syncthreads();
    for (int i = t; i < cnt; i += 512) {
        unsigned p = bp[i];
        unsigned pos = atomicAdd(&cur[(p >> 17) & (BINSZ - 1)], 1u);
        ssrt[pos] = p & 0x1FFFFu;
    }
    __syncthreads();

    // ---- per-wave independent: gather into A-fragments, then MFMA ----
    const int lane = t & 63;
    const int wave = t >> 6;              // 0..7
    const int rl   = lane & 15;
    const int kg   = lane >> 4;           // 0..3
    const int dn   = wave * 16 + rl;      // node in bin (0..127)
    const int node = node0 + dn;
    const float e = 1.0f + epsp[0];

    float a0[8], a1[8], a2[8], a3[8];     // 4 chunks: channels kk*32+kg*8
    if (node < N) {
        const unsigned short* base = xb + (size_t)node * DIM + kg * 8;
        bf16x8 v0 = *(const bf16x8*)(base + 0);
        bf16x8 v1 = *(const bf16x8*)(base + 32);
        bf16x8 v2 = *(const bf16x8*)(base + 64);
        bf16x8 v3 = *(const bf16x8*)(base + 96);
        #pragma unroll
        for (int q = 0; q < 8; ++q) {
            a0[q] = e * b2f((unsigned short)v0[q]);
            a1[q] = e * b2f((unsigned short)v1[q]);
            a2[q] = e * b2f((unsigned short)v2[q]);
            a3[q] = e * b2f((unsigned short)v3[q]);
        }
    } else {
        #pragma unroll
        for (int q = 0; q < 8; ++q) { a0[q] = a1[q] = a2[q] = a3[q] = 0.f; }
    }
    const int hn = (node < N) ? (int)hist[dn] : 0;
    const int b0 = (int)sbase[dn];

    int j = 0;
    for (; j + 2 <= hn; j += 2) {
        unsigned s0 = ssrt[b0 + j], s1 = ssrt[b0 + j + 1];
        const unsigned short* p0 = xb + (size_t)s0 * DIM + kg * 8;
        const unsigned short* p1 = xb + (size_t)s1 * DIM + kg * 8;
        bf16x8 r00 = *(const bf16x8*)(p0 + 0),  r01 = *(const bf16x8*)(p0 + 32);
        bf16x8 r02 = *(const bf16x8*)(p0 + 64), r03 = *(const bf16x8*)(p0 + 96);
        bf16x8 r10 = *(const bf16x8*)(p1 + 0),  r11 = *(const bf16x8*)(p1 + 32);
        bf16x8 r12 = *(const bf16x8*)(p1 + 64), r13 = *(const bf16x8*)(p1 + 96);
        #pragma unroll
        for (int q = 0; q < 8; ++q) {
            a0[q] += b2f((unsigned short)r00[q]) + b2f((unsigned short)r10[q]);
            a1[q] += b2f((unsigned short)r01[q]) + b2f((unsigned short)r11[q]);
            a2[q] += b2f((unsigned short)r02[q]) + b2f((unsigned short)r12[q]);
            a3[q] += b2f((unsigned short)r03[q]) + b2f((unsigned short)r13[q]);
        }
    }
    if (j < hn) {
        unsigned s0 = ssrt[b0 + j];
        const unsigned short* p0 = xb + (size_t)s0 * DIM + kg * 8;
        bf16x8 r00 = *(const bf16x8*)(p0 + 0),  r01 = *(const bf16x8*)(p0 + 32);
        bf16x8 r02 = *(const bf16x8*)(p0 + 64), r03 = *(const bf16x8*)(p0 + 96);
        #pragma unroll
        for (int q = 0; q < 8; ++q) {
            a0[q] += b2f((unsigned short)r00[q]);
            a1[q] += b2f((unsigned short)r01[q]);
            a2[q] += b2f((unsigned short)r02[q]);
            a3[q] += b2f((unsigned short)r03[q]);
        }
    }

    // convert to bf16 A-fragments
    bf16x8 f0, f1, f2, f3;
    #pragma unroll
    for (int q = 0; q < 8; ++q) {
        f0[q] = (short)f2b(a0[q]);
        f1[q] = (short)f2b(a1[q]);
        f2[q] = (short)f2b(a2[q]);
        f3[q] = (short)f2b(a3[q]);
    }

    // GEMM: B-fragments straight from global bf16 W^T (L1-resident, 32 KB)
    f32x4 c[8];
    #pragma unroll
    for (int nt = 0; nt < 8; ++nt) c[nt] = (f32x4)(0.f);
    #pragma unroll
    for (int nt = 0; nt < 8; ++nt) {
        const unsigned short* wrow = wT + (size_t)(nt * 16 + rl) * DIM + kg * 8;
        bf16x8 b0f = *(const bf16x8*)(wrow + 0);
        bf16x8 b1f = *(const bf16x8*)(wrow + 32);
        bf16x8 b2f_ = *(const bf16x8*)(wrow + 64);
        bf16x8 b3f = *(const bf16x8*)(wrow + 96);
        c[nt] = __builtin_amdgcn_mfma_f32_16x16x32_bf16(f0, b0f, c[nt], 0, 0, 0);
        c[nt] = __builtin_amdgcn_mfma_f32_16x16x32_bf16(f1, b1f, c[nt], 0, 0, 0);
        c[nt] = __builtin_amdgcn_mfma_f32_16x16x32_bf16(f2, b2f_, c[nt], 0, 0, 0);
        c[nt] = __builtin_amdgcn_mfma_f32_16x16x32_bf16(f3, b3f, c[nt], 0, 0, 0);
    }

    // epilogue: bias, store h1b (bf16), stats. C layout: col=lane&15, row=(lane>>4)*4+j
    const int orow0 = node0 + wave * 16 + kg * 4;
    #pragma unroll
    for (int nt = 0; nt < 8; ++nt) {
        int n = nt * 16 + rl;
        float bb = bias[n];
        float ls = 0.f, ls2 = 0.f;
        #pragma unroll
        for (int jj = 0; jj < 4; ++jj) {
            int r = orow0 + jj;
            if (r < N) {
                float v = c[nt][jj] + bb;
                h1b[(size_t)r * DIM + n] = f2b(v);
                ls += v; ls2 += v * v;
            }
        }
        ls  += __shfl_xor(ls, 16);  ls  += __shfl_xor(ls, 32);
        ls2 += __shfl_xor(ls2, 16); ls2 += __shfl_xor(ls2, 32);
        if (kg == 0) { atomicAdd(&red[n], ls); atomicAdd(&red[128 + n], ls2); }
    }
    __syncthreads();
    if (t < 256) atomicAdd(&stats[t], red[t]);
}

// ---------------------------------------------------------------- MFMA GEMM2: bf16 W^T from global, BN1 finalized in-block, + stats2
__global__ __launch_bounds__(1024)
void gemm2_mfma(const unsigned short* __restrict__ A, const unsigned short* __restrict__ wT,
                const float* __restrict__ bias,
                const float* __restrict__ stats_in, const float* __restrict__ gamma,
                const float* __restrict__ beta, float invN,
                unsigned short* __restrict__ outp, float* __restrict__ stats, int N)
{
    __shared__ float red[256];
    __shared__ float sss[256];
    const int tid = threadIdx.x;

    if (tid < 128) {
        float mu  = stats_in[tid] * invN;
        float var = fmaxf(stats_in[128 + tid] * invN - mu * mu, 0.f);
        float sc  = gamma[tid] * rsqrtf(var + 1e-5f);
        sss[tid]       = sc;
        sss[128 + tid] = beta[tid] - mu * sc;
    }
    if (tid < 256) red[tid] = 0.f;
    __syncthreads();

    const int lane = tid & 63;
    const int wave = tid >> 6;
    const int r0   = blockIdx.x * 256 + wave * 16;
    const int rl   = lane & 15;
    const int kg   = lane >> 4;
    int rr = r0 + rl;
    int rclamp = rr < N ? rr : N - 1;
    const unsigned short* arow = A + (size_t)rclamp * DIM + kg * 8;

    f32x4 acc[8];
    #pragma unroll
    for (int nt = 0; nt < 8; ++nt) acc[nt] = (f32x4)(0.f);

    #pragma unroll
    for (int kk = 0; kk < 128; kk += 32) {
        bf16x8 a8 = *(const bf16x8*)(arow + kk);
        {
            const int cb = kk + kg * 8;
            bf16x8 tt;
            #pragma unroll
            for (int j = 0; j < 8; ++j) {
                float f = b2f((unsigned short)a8[j]) * sss[cb + j] + sss[128 + cb + j];
                tt[j] = (short)f2b(fmaxf(f, 0.f));
            }
            a8 = tt;
        }
        const int ks = kk + kg * 8;
        #pragma unroll
        for (int nt = 0; nt < 8; ++nt) {
            bf16x8 b8 = *(const bf16x8*)(wT + (size_t)(nt * 16 + rl) * DIM + ks);
            acc[nt] = __builtin_amdgcn_mfma_f32_16x16x32_bf16(a8, b8, acc[nt], 0, 0, 0);
        }
    }

    const int orow0 = r0 + kg * 4;
    #pragma unroll
    for (int nt = 0; nt < 8; ++nt) {
        int n = nt * 16 + rl;
        float bb = bias[n];
        float ls = 0.f, ls2 = 0.f;
        #pragma unroll
        for (int j = 0; j < 4; ++j) {
            int r = orow0 + j;
            if (r < N) {
                float v = acc[nt][j] + bb;
                outp[(size_t)r * DIM + n] = f2b(v);
                ls += v; ls2 += v * v;
            }
        }
        ls  += __shfl_xor(ls, 16);  ls  += __shfl_xor(ls, 32);
        ls2 += __shfl_xor(ls2, 16); ls2 += __shfl_xor(ls2, 32);
        if (kg == 0) { atomicAdd(&red[n], ls); atomicAdd(&red[128 + n], ls2); }
    }
    __syncthreads();
    if (tid < 256) atomicAdd(&stats[tid], red[tid]);
}

// ---------------------------------------------------------------- final BN+ReLU: bf16 h2 -> fp32 out, BN finalized in-block
__global__ __launch_bounds__(256)
void bn_relu_out_b(const unsigned short* __restrict__ h2b,
                   const float* __restrict__ stats, const float* __restrict__ gamma,
                   const float* __restrict__ beta, float invN,
                   float* __restrict__ out, int n8)
{
    __shared__ float sss[256];
    const int tid = threadIdx.x;
    if (tid < 128) {
        float mu  = stats[tid] * invN;
        float var = fmaxf(stats[128 + tid] * invN - mu * mu, 0.f);
        float sc  = gamma[tid] * rsqrtf(var + 1e-5f);
        sss[tid]       = sc;
        sss[128 + tid] = beta[tid] - mu * sc;
    }
    __syncthreads();
    int i = blockIdx.x * 256 + tid;
    if (i >= n8) return;
    int c = (i * 8) & 127;
    bf16x8 v = *(const bf16x8*)(h2b + (size_t)i * 8);
    float4 o0, o1;
    o0.x = fmaxf(b2f((unsigned short)v[0]) * sss[c+0] + sss[128+c+0], 0.f);
    o0.y = fmaxf(b2f((unsigned short)v[1]) * sss[c+1] + sss[128+c+1], 0.f);
    o0.z = fmaxf(b2f((unsigned short)v[2]) * sss[c+2] + sss[128+c+2], 0.f);
    o0.w = fmaxf(b2f((unsigned short)v[3]) * sss[c+3] + sss[128+c+3], 0.f);
    o1.x = fmaxf(b2f((unsigned short)v[4]) * sss[c+4] + sss[128+c+4], 0.f);
    o1.y = fmaxf(b2f((unsigned short)v[5]) * sss[c+5] + sss[128+c+5], 0.f);
    o1.z = fmaxf(b2f((unsigned short)v[6]) * sss[c+6] + sss[128+c+6], 0.f);
    o1.w = fmaxf(b2f((unsigned short)v[7]) * sss[c+7] + sss[128+c+7], 0.f);
    ((float4*)out)[i * 2 + 0] = o0;
    ((float4*)out)[i * 2 + 1] = o1;
}

// ----------------------------------------------------------------
extern "C" void kernel_launch(void* const* d_in, const int* in_sizes, int n_in,
                              void* d_out, int out_size, void* d_ws, size_t ws_size,
                              hipStream_t stream) {
    const float* x    = (const float*)d_in[0];
    const int*   ei   = (const int*)  d_in[1];
    const float* W1   = (const float*)d_in[2];
    const float* b1   = (const float*)d_in[3];
    const float* g1   = (const float*)d_in[4];
    const float* be1  = (const float*)d_in[5];
    const float* W2   = (const float*)d_in[6];
    const float* b2   = (const float*)d_in[7];
    const float* g2   = (const float*)d_in[8];
    const float* be2  = (const float*)d_in[9];
    const float* epsp = (const float*)d_in[10];
    float* out = (float*)d_out;

    const int N = in_sizes[0] / DIM;   // 100000
    const int E = in_sizes[1] / 2;     // 1600000
    const int* src = ei;
    const int* dst = ei + E;
    const int nbins = (N + BINSZ - 1) >> BINSHIFT;   // 782

    // workspace layout (~76.9 MB):
    //   [0]     xb  [N*128 ushort]  25.6 MB
    //   [SZ]    h1b [N*128 ushort]  25.6 MB
    //   [2SZ]   binned [nbins*BCAP u32] 8 MB (dead after agg_gemm1) -> h2b overlays
    //   [3SZ]   gcur[1024 u32] | stats1[256 f] | stats2[256 f] | wT1[16384 bf16] | wT2[16384 bf16]
    const size_t SZ = (size_t)N * DIM * sizeof(unsigned short);
    char* w = (char*)d_ws;
    unsigned short* xb  = (unsigned short*)w;
    unsigned short* h1b = (unsigned short*)(w + SZ);
    unsigned* binned    = (unsigned*)(w + 2 * SZ);
    unsigned short* h2b = (unsigned short*)(w + 2 * SZ);
    unsigned* gcur      = (unsigned*)(w + 3 * SZ);
    float* stats1 = (float*)(gcur + 1024);
    float* stats2 = stats1 + 256;
    unsigned short* wT1 = (unsigned short*)(stats2 + 256);
    unsigned short* wT2 = wT1 + 128 * 128;

    const float invN = 1.0f / (float)N;
    const int n8 = N * DIM / 8;
    const int ebB = (E + EPB - 1) / EPB;            // 196 binning blocks
    const int castB = (n8 + 1023) / 1024;           // 1563 cast blocks

    // 1: zero gcur+stats1+stats2 (contiguous)
    hipMemsetAsync(gcur, 0, (1024 + 512) * sizeof(unsigned), stream);
    // 2: bin edges + cast x + transpose/cast W1,W2 (one kernel, roles by blockIdx)
    prep<<<ebB + castB + 8, 1024, 0, stream>>>(src, dst, gcur, binned, E, nbins,
                                               x, xb, n8, W1, W2, wT1, wT2, ebB, castB);
    // 3: fused sort + frag-gather + GEMM1 + stats1
    agg_gemm1<<<nbins, 512, 0, stream>>>(xb, epsp, gcur, binned, wT1, b1, h1b, stats1, N);
    // 4: GEMM2 (BN1+ReLU fused on input) + stats2
    const int gblocks = (N + 255) / 256;
    gemm2_mfma<<<gblocks, 1024, 0, stream>>>(h1b, wT2, b2, stats1, g1, be1, invN, h2b, stats2, N);
    // 5: BN2+ReLU -> fp32 out
    bn_relu_out_b<<<(n8 + 255) / 256, 256, 0, stream>>>(h2b, stats2, g2, be2, invN, out, n8);
}

// Round 11
// 204.575 us; speedup vs baseline: 1.0904x; 1.0904x over previous
//
#include <hip/hip_runtime.h>

#define DIM 128
#define BINSHIFT 7
#define BINSZ 128          // nodes per bin
#define BCAP 2560          // edges capacity per bin: Poisson(2048)+11sigma
#define EPB 8192           // edges per binning block

typedef __attribute__((ext_vector_type(8))) short bf16x8;
typedef __attribute__((ext_vector_type(4))) float f32x4;

__device__ inline unsigned short f2b(float f) {
    unsigned u = __builtin_bit_cast(unsigned, f);
    unsigned r = (u + 0x7FFFu + ((u >> 16) & 1u)) >> 16;
    return (unsigned short)r;
}
__device__ inline float b2f(unsigned short h) {
    unsigned u = ((unsigned)h) << 16;
    return __builtin_bit_cast(float, u);
}

// ---------------------------------------------------------------- prep: [0,ebB) bin edges | [ebB,ebB+castB) cast x | last 4: W1 -> bf16 W^T
__global__ __launch_bounds__(1024)
void prep(const int* __restrict__ src, const int* __restrict__ dst,
          unsigned* __restrict__ gcur, unsigned* __restrict__ binned, int E, int nbins,
          const float* __restrict__ x, unsigned short* __restrict__ xb, int n8,
          const float* __restrict__ W1, unsigned short* __restrict__ wT1,
          int ebB, int castB)
{
    const int t = threadIdx.x;
    const int bid = blockIdx.x;
    if (bid < ebB) {
        // ---- binning role (proven) ----
        __shared__ unsigned hist[1024];
        __shared__ unsigned base[1024];
        const long long bb = (long long)bid * EPB;
        if (t < nbins) hist[t] = 0;
        __syncthreads();
        unsigned pk[8], pos[8];
        int bn[8];
        bool ok[8];
        #pragma unroll
        for (int i = 0; i < 8; ++i) {
            long long idx = bb + i * 1024 + t;
            ok[i] = idx < E;
            if (ok[i]) {
                int s = src[idx], d = dst[idx];
                pk[i] = ((unsigned)(d & (BINSZ - 1)) << 17) | (unsigned)s;
                bn[i] = d >> BINSHIFT;
                pos[i] = atomicAdd(&hist[bn[i]], 1u);
            }
        }
        __syncthreads();
        if (t < nbins) base[t] = (unsigned)t * BCAP + atomicAdd(&gcur[t], hist[t]);
        __syncthreads();
        #pragma unroll
        for (int i = 0; i < 8; ++i) {
            if (ok[i]) {
                unsigned off = base[bn[i]] + pos[i];
                if (off < (unsigned)(bn[i] + 1) * BCAP) binned[off] = pk[i];
            }
        }
    } else if (bid < ebB + castB) {
        // ---- cast x role ----
        int i = (bid - ebB) * 1024 + t;
        if (i >= n8) return;
        float4 a = ((const float4*)x)[i * 2];
        float4 b = ((const float4*)x)[i * 2 + 1];
        bf16x8 o;
        o[0] = (short)f2b(a.x); o[1] = (short)f2b(a.y); o[2] = (short)f2b(a.z); o[3] = (short)f2b(a.w);
        o[4] = (short)f2b(b.x); o[5] = (short)f2b(b.y); o[6] = (short)f2b(b.z); o[7] = (short)f2b(b.w);
        ((bf16x8*)xb)[i] = o;
    } else {
        // ---- W1 transpose+cast role: 4 blocks ----
        int r = bid - ebB - castB;                 // 0..3
        int idx = r * 1024 + t;                    // 0..4095
        int n = idx >> 5, k = (idx & 31) * 4;
        #pragma unroll
        for (int i = 0; i < 4; ++i)
            wT1[n * 128 + k + i] = f2b(W1[(size_t)(k + i) * 128 + n]);
    }
}

// ---------------------------------------------------------------- per-bin counting sort -> srt (src grouped by node) + per-node base/cnt
__global__ __launch_bounds__(512)
void bin_sort(const unsigned* __restrict__ gcur, const unsigned* __restrict__ binned,
              unsigned* __restrict__ srt, unsigned* __restrict__ gbase,
              unsigned* __restrict__ ghist)
{
    __shared__ unsigned hist[BINSZ];
    __shared__ unsigned base[BINSZ];
    __shared__ unsigned cur[BINSZ];
    __shared__ unsigned wtot_s;
    const int t = threadIdx.x;
    const int bin = blockIdx.x;

    if (t < BINSZ) hist[t] = 0;
    __syncthreads();

    int cnt = (int)gcur[bin];
    if (cnt > BCAP) cnt = BCAP;
    const unsigned* __restrict__ bp = binned + (size_t)bin * BCAP;

    for (int i = t; i < cnt; i += 512)
        atomicAdd(&hist[(bp[i] >> 17) & (BINSZ - 1)], 1u);
    __syncthreads();
    // parallel exclusive scan (two waves, shfl_up)
    unsigned iv = 0, hv = 0;
    if (t < BINSZ) {
        hv = hist[t];
        iv = hv;
        #pragma unroll
        for (int d = 1; d < 64; d <<= 1) {
            unsigned u = __shfl_up(iv, d);
            if ((t & 63) >= d) iv += u;
        }
        if (t == 63) wtot_s = iv;
    }
    __syncthreads();
    if (t < BINSZ) {
        unsigned ex = iv - hv + ((t >= 64) ? wtot_s : 0u);
        base[t] = ex;
        cur[t] = ex;
    }
    __syncthreads();
    unsigned* __restrict__ sp = srt + (size_t)bin * BCAP;
    for (int i = t; i < cnt; i += 512) {
        unsigned p = bp[i];
        unsigned pos = atomicAdd(&cur[(p >> 17) & (BINSZ - 1)], 1u);
        sp[pos] = p & 0x1FFFFu;
    }
    if (t < BINSZ) {
        gbase[bin * BINSZ + t] = base[t];
        ghist[bin * BINSZ + t] = hist[t];
    }
}

// ---------------------------------------------------------------- fused gather (-> swizzled LDS A) + MFMA GEMM1; LDS = 34 KB -> 4 blocks/CU
// 512 threads, one bin of 128 nodes. Gather: 16 lanes/node x 8 ch (R9-proven mapping).
__global__ __launch_bounds__(512)
void agg_gemm1(const unsigned short* __restrict__ xb, const float* __restrict__ epsp,
               const unsigned* __restrict__ srt, const unsigned* __restrict__ gbase,
               const unsigned* __restrict__ ghist,
               const unsigned short* __restrict__ wT, const float* __restrict__ bias,
               unsigned short* __restrict__ h1b, float* __restrict__ stats, int N)
{
    __shared__ unsigned short sA[128 * 128];   // 32 KB, swizzled A tile
    __shared__ unsigned sbase[BINSZ], shist[BINSZ];
    __shared__ float red[256];
    const int t = threadIdx.x;
    const int bin = blockIdx.x;
    const int node0 = bin << BINSHIFT;

    if (t < BINSZ) {
        sbase[t] = gbase[bin * BINSZ + t];
        shist[t] = ghist[bin * BINSZ + t];
    }
    if (t < 256) red[t] = 0.f;
    __syncthreads();

    // ---- gather phase: 16 lanes/node x 8 ch, 4 sweeps of 32 nodes -> swizzled sA ----
    const unsigned* __restrict__ spb = srt + (size_t)bin * BCAP;
    const float e = 1.0f + epsp[0];
    const int g8 = t & 15;          // channel chunk 0..15
    const int g  = g8 * 8;
    const int slot = t >> 4;        // 0..31
    for (int sw = 0; sw < 4; ++sw) {
        int dn = sw * 32 + slot;
        int node = node0 + dn;
        float acc[8];
        if (node < N) {
            bf16x8 v0 = *(const bf16x8*)(xb + (size_t)node * DIM + g);
            #pragma unroll
            for (int q = 0; q < 8; ++q) acc[q] = e * b2f((unsigned short)v0[q]);
            const unsigned* __restrict__ sp = spb + sbase[dn];
            const int hn = (int)shist[dn];
            int j = 0;
            for (; j + 8 <= hn; j += 8) {
                unsigned s0 = sp[j+0], s1 = sp[j+1], s2 = sp[j+2], s3 = sp[j+3];
                unsigned s4 = sp[j+4], s5 = sp[j+5], s6 = sp[j+6], s7 = sp[j+7];
                bf16x8 r0 = *(const bf16x8*)(xb + (size_t)s0 * DIM + g);
                bf16x8 r1 = *(const bf16x8*)(xb + (size_t)s1 * DIM + g);
                bf16x8 r2 = *(const bf16x8*)(xb + (size_t)s2 * DIM + g);
                bf16x8 r3 = *(const bf16x8*)(xb + (size_t)s3 * DIM + g);
                bf16x8 r4 = *(const bf16x8*)(xb + (size_t)s4 * DIM + g);
                bf16x8 r5 = *(const bf16x8*)(xb + (size_t)s5 * DIM + g);
                bf16x8 r6 = *(const bf16x8*)(xb + (size_t)s6 * DIM + g);
                bf16x8 r7 = *(const bf16x8*)(xb + (size_t)s7 * DIM + g);
                #pragma unroll
                for (int q = 0; q < 8; ++q)
                    acc[q] += b2f((unsigned short)r0[q]) + b2f((unsigned short)r1[q])
                            + b2f((unsigned short)r2[q]) + b2f((unsigned short)r3[q])
                            + b2f((unsigned short)r4[q]) + b2f((unsigned short)r5[q])
                            + b2f((unsigned short)r6[q]) + b2f((unsigned short)r7[q]);
            }
            for (; j + 2 <= hn; j += 2) {
                unsigned s0 = sp[j+0], s1 = sp[j+1];
                bf16x8 r0 = *(const bf16x8*)(xb + (size_t)s0 * DIM + g);
                bf16x8 r1 = *(const bf16x8*)(xb + (size_t)s1 * DIM + g);
                #pragma unroll
                for (int q = 0; q < 8; ++q)
                    acc[q] += b2f((unsigned short)r0[q]) + b2f((unsigned short)r1[q]);
            }
            for (; j < hn; ++j) {
                unsigned s0 = sp[j];
                bf16x8 r0 = *(const bf16x8*)(xb + (size_t)s0 * DIM + g);
                #pragma unroll
                for (int q = 0; q < 8; ++q) acc[q] += b2f((unsigned short)r0[q]);
            }
        } else {
            #pragma unroll
            for (int q = 0; q < 8; ++q) acc[q] = 0.f;
        }
        bf16x8 o;
        #pragma unroll
        for (int q = 0; q < 8; ++q) o[q] = (short)f2b(acc[q]);
        // swizzled store: chunk g8 of row dn -> slot (g8 ^ (dn&15))
        *(bf16x8*)&sA[dn * 128 + ((g8 ^ (dn & 15)) << 3)] = o;
    }
    __syncthreads();

    // ---- GEMM phase: 8 waves x 16 rows; A from sA, B-frags from global bf16 W^T ----
    const int lane = t & 63;
    const int wave = t >> 6;               // 0..7
    const int rl   = lane & 15;
    const int kg   = lane >> 4;            // 0..3
    const int r0   = wave * 16;            // row-in-bin

    // A-fragments for the 4 k-chunks (de-swizzle with ^rl since (r0+rl)&15 == rl)
    bf16x8 a0 = *(const bf16x8*)&sA[(r0 + rl) * 128 + (((0 * 4 + kg) ^ rl) << 3)];
    bf16x8 a1 = *(const bf16x8*)&sA[(r0 + rl) * 128 + (((1 * 4 + kg) ^ rl) << 3)];
    bf16x8 a2 = *(const bf16x8*)&sA[(r0 + rl) * 128 + (((2 * 4 + kg) ^ rl) << 3)];
    bf16x8 a3 = *(const bf16x8*)&sA[(r0 + rl) * 128 + (((3 * 4 + kg) ^ rl) << 3)];

    f32x4 c[8];
    #pragma unroll
    for (int nt = 0; nt < 8; ++nt) c[nt] = (f32x4)(0.f);
    #pragma unroll
    for (int nt = 0; nt < 8; ++nt) {
        const unsigned short* wrow = wT + (size_t)(nt * 16 + rl) * DIM + kg * 8;
        bf16x8 w0 = *(const bf16x8*)(wrow + 0);
        bf16x8 w1 = *(const bf16x8*)(wrow + 32);
        bf16x8 w2 = *(const bf16x8*)(wrow + 64);
        bf16x8 w3 = *(const bf16x8*)(wrow + 96);
        c[nt] = __builtin_amdgcn_mfma_f32_16x16x32_bf16(a0, w0, c[nt], 0, 0, 0);
        c[nt] = __builtin_amdgcn_mfma_f32_16x16x32_bf16(a1, w1, c[nt], 0, 0, 0);
        c[nt] = __builtin_amdgcn_mfma_f32_16x16x32_bf16(a2, w2, c[nt], 0, 0, 0);
        c[nt] = __builtin_amdgcn_mfma_f32_16x16x32_bf16(a3, w3, c[nt], 0, 0, 0);
    }

    // epilogue: bias, store h1b (bf16), stats. C layout: col=lane&15, row=(lane>>4)*4+j
    const int orow0 = node0 + r0 + kg * 4;
    #pragma unroll
    for (int nt = 0; nt < 8; ++nt) {
        int n = nt * 16 + rl;
        float bb = bias[n];
        float ls = 0.f, ls2 = 0.f;
        #pragma unroll
        for (int jj = 0; jj < 4; ++jj) {
            int r = orow0 + jj;
            if (r < N) {
                float v = c[nt][jj] + bb;
                h1b[(size_t)r * DIM + n] = f2b(v);
                ls += v; ls2 += v * v;
            }
        }
        ls  += __shfl_xor(ls, 16);  ls  += __shfl_xor(ls, 32);
        ls2 += __shfl_xor(ls2, 16); ls2 += __shfl_xor(ls2, 32);
        if (kg == 0) { atomicAdd(&red[n], ls); atomicAdd(&red[128 + n], ls2); }
    }
    __syncthreads();
    if (t < 256) atomicAdd(&stats[t], red[t]);
}

// ---------------------------------------------------------------- MFMA GEMM2 (R9-proven): LDS sWT staging, BN1 finalized in-block, + stats2
__global__ __launch_bounds__(1024)
void gemm2_mfma(const unsigned short* __restrict__ A, const float* __restrict__ Wf,
                const float* __restrict__ bias,
                const float* __restrict__ stats_in, const float* __restrict__ gamma,
                const float* __restrict__ beta, float invN,
                unsigned short* __restrict__ outp, float* __restrict__ stats, int N)
{
    __shared__ unsigned short sWT[128 * 128];
    __shared__ float red[256];
    __shared__ float sss[256];
    const int tid = threadIdx.x;

    if (tid < 128) {
        float mu  = stats_in[tid] * invN;
        float var = fmaxf(stats_in[128 + tid] * invN - mu * mu, 0.f);
        float sc  = gamma[tid] * rsqrtf(var + 1e-5f);
        sss[tid]       = sc;
        sss[128 + tid] = beta[tid] - mu * sc;
    }
    #pragma unroll
    for (int i = 0; i < 4; ++i) {
        int idx = (i * 1024 + tid) * 4;
        float4 w = *(const float4*)&Wf[idx];
        int k = idx >> 7, n0 = idx & 127;
        sWT[(n0 + 0) * 128 + (k ^ (((n0 + 0) & 7) << 3))] = f2b(w.x);
        sWT[(n0 + 1) * 128 + (k ^ (((n0 + 1) & 7) << 3))] = f2b(w.y);
        sWT[(n0 + 2) * 128 + (k ^ (((n0 + 2) & 7) << 3))] = f2b(w.z);
        sWT[(n0 + 3) * 128 + (k ^ (((n0 + 3) & 7) << 3))] = f2b(w.w);
    }
    if (tid < 256) red[tid] = 0.f;
    __syncthreads();

    const int lane = tid & 63;
    const int wave = tid >> 6;
    const int r0   = blockIdx.x * 256 + wave * 16;
    const int rl   = lane & 15;
    const int kg   = lane >> 4;
    int rr = r0 + rl;
    int rclamp = rr < N ? rr : N - 1;
    const unsigned short* arow = A + (size_t)rclamp * DIM + kg * 8;

    f32x4 acc[8];
    #pragma unroll
    for (int nt = 0; nt < 8; ++nt) acc[nt] = (f32x4)(0.f);

    #pragma unroll
    for (int kk = 0; kk < 128; kk += 32) {
        bf16x8 a8 = *(const bf16x8*)(arow + kk);
        {
            const int cb = kk + kg * 8;
            bf16x8 tt;
            #pragma unroll
            for (int j = 0; j < 8; ++j) {
                float f = b2f((unsigned short)a8[j]) * sss[cb + j] + sss[128 + cb + j];
                tt[j] = (short)f2b(fmaxf(f, 0.f));
            }
            a8 = tt;
        }
        const int ks = kk + kg * 8;
        #pragma unroll
        for (int nt = 0; nt < 8; ++nt) {
            int n = nt * 16 + rl;
            bf16x8 b8 = *(const bf16x8*)&sWT[n * 128 + (ks ^ ((n & 7) << 3))];
            acc[nt] = __builtin_amdgcn_mfma_f32_16x16x32_bf16(a8, b8, acc[nt], 0, 0, 0);
        }
    }

    const int orow0 = r0 + kg * 4;
    #pragma unroll
    for (int nt = 0; nt < 8; ++nt) {
        int n = nt * 16 + rl;
        float bb = bias[n];
        float ls = 0.f, ls2 = 0.f;
        #pragma unroll
        for (int j = 0; j < 4; ++j) {
            int r = orow0 + j;
            if (r < N) {
                float v = acc[nt][j] + bb;
                outp[(size_t)r * DIM + n] = f2b(v);
                ls += v; ls2 += v * v;
            }
        }
        ls  += __shfl_xor(ls, 16);  ls  += __shfl_xor(ls, 32);
        ls2 += __shfl_xor(ls2, 16); ls2 += __shfl_xor(ls2, 32);
        if (kg == 0) { atomicAdd(&red[n], ls); atomicAdd(&red[128 + n], ls2); }
    }
    __syncthreads();
    if (tid < 256) atomicAdd(&stats[tid], red[tid]);
}

// ---------------------------------------------------------------- final BN+ReLU: bf16 h2 -> fp32 out, BN finalized in-block
__global__ __launch_bounds__(256)
void bn_relu_out_b(const unsigned short* __restrict__ h2b,
                   const float* __restrict__ stats, const float* __restrict__ gamma,
                   const float* __restrict__ beta, float invN,
                   float* __restrict__ out, int n8)
{
    __shared__ float sss[256];
    const int tid = threadIdx.x;
    if (tid < 128) {
        float mu  = stats[tid] * invN;
        float var = fmaxf(stats[128 + tid] * invN - mu * mu, 0.f);
        float sc  = gamma[tid] * rsqrtf(var + 1e-5f);
        sss[tid]       = sc;
        sss[128 + tid] = beta[tid] - mu * sc;
    }
    __syncthreads();
    int i = blockIdx.x * 256 + tid;
    if (i >= n8) return;
    int c = (i * 8) & 127;
    bf16x8 v = *(const bf16x8*)(h2b + (size_t)i * 8);
    float4 o0, o1;
    o0.x = fmaxf(b2f((unsigned short)v[0]) * sss[c+0] + sss[128+c+0], 0.f);
    o0.y = fmaxf(b2f((unsigned short)v[1]) * sss[c+1] + sss[128+c+1], 0.f);
    o0.z = fmaxf(b2f((unsigned short)v[2]) * sss[c+2] + sss[128+c+2], 0.f);
    o0.w = fmaxf(b2f((unsigned short)v[3]) * sss[c+3] + sss[128+c+3], 0.f);
    o1.x = fmaxf(b2f((unsigned short)v[4]) * sss[c+4] + sss[128+c+4], 0.f);
    o1.y = fmaxf(b2f((unsigned short)v[5]) * sss[c+5] + sss[128+c+5], 0.f);
    o1.z = fmaxf(b2f((unsigned short)v[6]) * sss[c+6] + sss[128+c+6], 0.f);
    o1.w = fmaxf(b2f((unsigned short)v[7]) * sss[c+7] + sss[128+c+7], 0.f);
    ((float4*)out)[i * 2 + 0] = o0;
    ((float4*)out)[i * 2 + 1] = o1;
}

// ----------------------------------------------------------------
extern "C" void kernel_launch(void* const* d_in, const int* in_sizes, int n_in,
                              void* d_out, int out_size, void* d_ws, size_t ws_size,
                              hipStream_t stream) {
    const float* x    = (const float*)d_in[0];
    const int*   ei   = (const int*)  d_in[1];
    const float* W1   = (const float*)d_in[2];
    const float* b1   = (const float*)d_in[3];
    const float* g1   = (const float*)d_in[4];
    const float* be1  = (const float*)d_in[5];
    const float* W2   = (const float*)d_in[6];
    const float* b2   = (const float*)d_in[7];
    const float* g2   = (const float*)d_in[8];
    const float* be2  = (const float*)d_in[9];
    const float* epsp = (const float*)d_in[10];
    float* out = (float*)d_out;

    const int N = in_sizes[0] / DIM;   // 100000
    const int E = in_sizes[1] / 2;     // 1600000
    const int* src = ei;
    const int* dst = ei + E;
    const int nbins = (N + BINSZ - 1) >> BINSHIFT;   // 782

    // workspace layout (~76.9 MB):
    //   [0]     xb  [N*128 ushort]  25.6 MB
    //   [SZ]    h1b [N*128 ushort]  25.6 MB
    //   [2SZ]   regC: binned(8MB) | srt(8MB) | gbase(.4) | ghist(.4)  (dead after agg_gemm1)
    //           h2b overlays regC
    //   [3SZ]   gcur[1024 u32] | stats1[256 f] | stats2[256 f] | wT1[16384 bf16]
    const size_t SZ = (size_t)N * DIM * sizeof(unsigned short);
    char* w = (char*)d_ws;
    unsigned short* xb  = (unsigned short*)w;
    unsigned short* h1b = (unsigned short*)(w + SZ);
    unsigned* binned    = (unsigned*)(w + 2 * SZ);
    unsigned* srt       = binned + (size_t)nbins * BCAP;
    unsigned* gbase     = srt + (size_t)nbins * BCAP;
    unsigned* ghist     = gbase + (size_t)nbins * BINSZ;
    unsigned short* h2b = (unsigned short*)(w + 2 * SZ);
    unsigned* gcur      = (unsigned*)(w + 3 * SZ);
    float* stats1 = (float*)(gcur + 1024);
    float* stats2 = stats1 + 256;
    unsigned short* wT1 = (unsigned short*)(stats2 + 256);

    const float invN = 1.0f / (float)N;
    const int n8 = N * DIM / 8;
    const int ebB = (E + EPB - 1) / EPB;            // 196 binning blocks
    const int castB = (n8 + 1023) / 1024;           // 1563 cast blocks

    // 1: zero gcur+stats1+stats2 (contiguous)
    hipMemsetAsync(gcur, 0, (1024 + 512) * sizeof(unsigned), stream);
    // 2: bin edges + cast x + transpose/cast W1 (one kernel, roles by blockIdx)
    prep<<<ebB + castB + 4, 1024, 0, stream>>>(src, dst, gcur, binned, E, nbins,
                                               x, xb, n8, W1, wT1, ebB, castB);
    // 3: per-bin counting sort -> global CSR
    bin_sort<<<nbins, 512, 0, stream>>>(gcur, binned, srt, gbase, ghist);
    // 4: fused gather->LDS + GEMM1 + stats1 (34 KB LDS -> 4 blocks/CU)
    agg_gemm1<<<nbins, 512, 0, stream>>>(xb, epsp, srt, gbase, ghist, wT1, b1, h1b, stats1, N);
    // 5: GEMM2 (BN1+ReLU fused on input) + stats2
    const int gblocks = (N + 255) / 256;
    gemm2_mfma<<<gblocks, 1024, 0, stream>>>(h1b, W2, b2, stats1, g1, be1, invN, h2b, stats2, N);
    // 6: BN2+ReLU -> fp32 out
    bn_relu_out_b<<<(n8 + 255) / 256, 256, 0, stream>>>(h2b, stats2, g2, be2, invN, out, n8);
}